// Round 9
// baseline (2000.858 us; speedup 1.0000x reference)
//
#include <hip/hip_runtime.h>
#include <hip/hip_bf16.h>

// CustomLSTMModel: emb(32000x300 fp32, pad_idx=0) -> LSTM(300->512, 512 steps, B=256, fp32)
//                  -> FC(512->7, fp32). tokens int32; out fp32 [256,7].
// Internal: bf16 MFMA (RNE), fp32 accum/c/biases/FC. absmax ~1e-3.
//
// R15: R14's L2-exchange failed correctness (stale h, absmax 4e-2) -> LLC (agent-scope)
// exchange is the only provably-correct path; reverted. The per-step serial chain
// (poll-RTT + h-RTT + hh/elem + store-drain ~ 7260cy) can't be compressed in-place
// (R8-R14). Instead: HIDE it behind a second independent recurrence.
//  - Each block serves TWO groups: pair p = bid&7 -> groups {2p, 2p+1} (16 batches each),
//    32 blocks/pair, 16 units/block/group. Iteration = A-half then B-half; each half is
//    a full R10-style step for that group. Period amortizes: poll flag for G was
//    published a full half (~2400cy) earlier AND wave0 pre-issues the flag load in the
//    opposite half -> first check passes on arrived data (fallback loop retained).
//    h-RTT partially hides under that group's ih-MFMAs.
//  - A-fragments SHARED between groups (same weight rows): aih[10]+ahh[16] only.
//    MFMA/wave/iteration unchanged (52); B-reads double (LDS headroom exists).
//  - Exchange invariants identical to R10 per group: LLC-routed relaxed agent atomics,
//    parity ping-pong hbuf, poll target t+1, u64 LDS-bounce writeback (32B/row chunks,
//    4 contiguous u64), wave0-only poll + release barrier, 0xAAAAAAAA poison < 1.
// Per-half barriers: S2a (poll release), S2b (h staged), S3a (scr), S3b (store drain).

typedef unsigned short ushort_t;
typedef unsigned long long u64_t;
typedef __bf16 bf16x8 __attribute__((ext_vector_type(8)));
typedef unsigned short u16x8v __attribute__((ext_vector_type(8)));
typedef float f32x4 __attribute__((ext_vector_type(4)));

#define XS 328    // x row stride in ushorts (656B, 16B-aligned; 320 data+zero-pad used)
#define HS 520    // h row stride in ushorts (1040B, 16B-aligned; 512 used)
#define SCR2 20   // scratch row stride in ushorts (40B; 16 used)

__device__ __forceinline__ float sigmoidf_(float x) { return 1.0f / (1.0f + __expf(-x)); }
__device__ __forceinline__ float tanhf_(float x)    { return 1.0f - 2.0f / (__expf(2.0f * x) + 1.0f); }

__device__ __forceinline__ ushort_t f2bf(float f) {   // RNE; inputs finite
    unsigned u = __builtin_bit_cast(unsigned, f);
    unsigned r = (u + 0x7FFFu + ((u >> 16) & 1u)) >> 16;
    return (ushort_t)r;
}
__device__ __forceinline__ float bf2f(ushort_t u) {
    unsigned v = ((unsigned)u) << 16;
    return __builtin_bit_cast(float, v);
}

// LLC-coherent (cache-bypassing) accessors — relaxed agent atomics, no fences.
__device__ __forceinline__ u64_t g_load64(const u64_t* p) {
    return __hip_atomic_load(p, __ATOMIC_RELAXED, __HIP_MEMORY_SCOPE_AGENT);
}
__device__ __forceinline__ void g_store64(u64_t* p, u64_t v) {
    __hip_atomic_store(p, v, __ATOMIC_RELAXED, __HIP_MEMORY_SCOPE_AGENT);
}
__device__ __forceinline__ int g_load_flag(const int* p) {
    return __hip_atomic_load(p, __ATOMIC_RELAXED, __HIP_MEMORY_SCOPE_AGENT);
}
__device__ __forceinline__ void g_store_flag(int* p, int v) {
    __hip_atomic_store(p, v, __ATOMIC_RELAXED, __HIP_MEMORY_SCOPE_AGENT);
}

__global__ __launch_bounds__(256, 1)
void lstm_fused_kernel(const int* __restrict__ tokens,    // [256][512]
                       const float* __restrict__ emb,     // [32000][300]
                       const float* __restrict__ Wih,     // [2048][300]
                       const float* __restrict__ bih,     // [2048]
                       const float* __restrict__ Whh,     // [2048][512]
                       const float* __restrict__ bhh,     // [2048]
                       const float* __restrict__ Wfc,     // [7][512]
                       const float* __restrict__ bfc,     // [7]
                       float* __restrict__ out,           // [256][7]
                       int* __restrict__ flags,           // [512]: pair p -> [64p..64p+64)
                       ushort_t* __restrict__ hbuf)       // [2][256][512] bf16
{
    __shared__ ushort_t xA_lds[16 * XS];   // 10496 B
    __shared__ ushort_t xB_lds[16 * XS];
    __shared__ ushort_t hA_lds[16 * HS];   // 16640 B
    __shared__ ushort_t hB_lds[16 * HS];
    __shared__ ushort_t h_scr[16 * SCR2];  // 640 B

    const int tid = threadIdx.x;
    const int bid = blockIdx.x;
    const int p    = bid & 7;      // pair 0..7 (XCD-aligned under round-robin: harmless hint)
    const int ib   = bid >> 3;     // block-in-pair 0..31 -> unit slice
    const int Bg0A = 32 * p;       // group A batches [Bg0A, Bg0A+16)
    const int Bg0B = 32 * p + 16;  // group B batches
    const int U0   = ib * 16;      // 16 units per block per group
    const int lane = tid & 63;
    const int wv   = tid >> 6;     // wave 0..3; wave owns 1 M-tile (16 gate rows) per group
    const int lm   = lane & 15;
    const int q    = lane >> 4;

    // ---- preload A-fragments (SHARED between groups), fp32 -> bf16 RNE ----
    // Block covers 64 gate rows per group: rp = 16*wv + lm; unit_local = rp>>2, gate = rp&3.
    bf16x8 aih[10];
    bf16x8 ahh[16];
    {
        const int rp   = 16 * wv + lm;
        const int gi   = rp & 3;
        const int up   = rp >> 2;               // unit_local 0..15
        const int grow = gi * 512 + U0 + up;    // global gate row
#pragma unroll
        for (int kc = 0; kc < 10; ++kc) {
            u16x8v tmp;
#pragma unroll
            for (int j = 0; j < 8; ++j) {
                int col = 32 * kc + 8 * q + j;
                tmp[j] = (col < 300) ? f2bf(Wih[grow * 300 + col]) : (ushort_t)0;
            }
            aih[kc] = __builtin_bit_cast(bf16x8, tmp);
        }
#pragma unroll
        for (int kc = 0; kc < 16; ++kc) {
            u16x8v tmp;
#pragma unroll
            for (int j = 0; j < 8; ++j) {
                int col = 32 * kc + 8 * q + j;
                tmp[j] = f2bf(Whh[grow * 512 + col]);
            }
            ahh[kc] = __builtin_bit_cast(bf16x8, tmp);
        }
    }

    // ---- per-lane biases: lane's unit = U0 + 4*wv + q (same for both groups) ----
    float bias0, bias1, bias2, bias3;
    {
        const int unit = U0 + 4 * wv + q;
        bias0 = bih[0 * 512 + unit] + bhh[0 * 512 + unit];
        bias1 = bih[1 * 512 + unit] + bhh[1 * 512 + unit];
        bias2 = bih[2 * 512 + unit] + bhh[2 * 512 + unit];
        bias3 = bih[3 * 512 + unit] + bhh[3 * 512 + unit];
    }

    // ---- init: zero h parity-0 for our 32 batch rows x 16 units (32B/row) ----
    if (tid < 128) {
        int r = tid >> 2;        // batch row 0..31 (covers A then B: contiguous)
        int d = tid & 3;         // 4 u64 = 16 units
        g_store64((u64_t*)(hbuf + (size_t)(Bg0A + r) * 512 + U0 + 4 * d), 0ull);
    }
    __syncthreads();             // drains stores before publish
    if (tid == 0) {
        g_store_flag(&flags[p * 64 + ib], 1);         // A flag
        g_store_flag(&flags[p * 64 + 32 + ib], 1);    // B flag
    }

    const int* mfA = &flags[p * 64 + (lane & 31)];
    const int* mfB = &flags[p * 64 + 32 + (lane & 31)];
    int* pubA = &flags[p * 64 + ib];
    int* pubB = &flags[p * 64 + 32 + ib];
    float cA = 0.0f, cB = 0.0f;
    int vA0 = 0, vB0 = 0;        // pre-issued flag values (wave0)
    if (wv == 0) vA0 = g_load_flag(mfA);

    // ---- x prefetch state: thread handles row xr = tid>>4, elements xln+16k ----
    const int xr  = tid >> 4;
    const int xln = tid & 15;
    const int* toksA = tokens + (size_t)(Bg0A + xr) * 512;
    const int* toksB = tokens + (size_t)(Bg0B + xr) * 512;
    float2 xpA[10], xpB[10];
    int tokA_stage, tokA_nxt, tokB_stage, tokB_nxt;
    {
        // stage xA_0 directly
        int tk0 = toksA[0];
        const float2* s0 = (const float2*)(emb + (size_t)tk0 * 300);
        const bool tz0 = (tk0 != 0);
        unsigned int* dst = (unsigned int*)(xA_lds + xr * XS);
#pragma unroll
        for (int k = 0; k < 10; ++k) {
            int i = xln + 16 * k;
            float2 v2 = (tz0 && i < 150) ? s0[i] : (float2){0.f, 0.f};
            unsigned int v = 0u;
            if (tz0 && i < 150)
                v = (unsigned int)f2bf(v2.x) | ((unsigned int)f2bf(v2.y) << 16);
            dst[i] = v;
        }
        // xpA <- emb[tokenA(1)]; xpB <- emb[tokenB(0)]
        tokA_stage = toksA[1];
        const float2* sA = (const float2*)(emb + (size_t)tokA_stage * 300);
#pragma unroll
        for (int k = 0; k < 10; ++k) { int i = xln + 16 * k; if (i < 150) xpA[k] = sA[i]; }
        tokA_nxt = toksA[2];
        tokB_stage = toksB[0];
        const float2* sB = (const float2*)(emb + (size_t)tokB_stage * 300);
#pragma unroll
        for (int k = 0; k < 10; ++k) { int i = xln + 16 * k; if (i < 150) xpB[k] = sB[i]; }
        tokB_nxt = toksB[1];
    }
    __syncthreads();   // xA_0 staged

    for (int t = 0; t < 512; ++t) {
        // ================= A-half: group A advances step t =================
        if (wv == 0) {
            const int target = t + 1;
            if (!__all(vA0 >= target)) {
                while (true) {
                    int v = g_load_flag(mfA);
                    if (__all(v >= target)) break;
                    __builtin_amdgcn_s_sleep(1);
                }
            }
            asm volatile("" ::: "memory");
        }
        __syncthreads();   // S2a-A

        // issue hA loads (oldest in FIFO)
        u64_t htmp[8];
        {
            const u64_t* hsrc = (const u64_t*)(hbuf + (size_t)(t & 1) * (256 * 512)
                                               + (size_t)(Bg0A + xr) * 512);
#pragma unroll
            for (int k = 0; k < 8; ++k) htmp[k] = g_load64(hsrc + xln + 16 * k);
        }
        // stage xB_t (consumes xpB); then refill xpB for t+1
        {
            const bool tz = (tokB_stage != 0);
            unsigned int* dst = (unsigned int*)(xB_lds + xr * XS);
#pragma unroll
            for (int k = 0; k < 10; ++k) {
                int i = xln + 16 * k;
                unsigned int v = 0u;
                if (tz && i < 150)
                    v = (unsigned int)f2bf(xpB[k].x) | ((unsigned int)f2bf(xpB[k].y) << 16);
                dst[i] = v;
            }
            tokB_stage = tokB_nxt;
            const float2* s2 = (const float2*)(emb + (size_t)tokB_stage * 300);
#pragma unroll
            for (int k = 0; k < 10; ++k) { int i = xln + 16 * k; if (i < 150) xpB[k] = s2[i]; }
            tokB_nxt = toksB[(t + 2 < 512) ? (t + 2) : 511];
        }
        // ih-A (hides hA latency)
        f32x4 acc = {0.f, 0.f, 0.f, 0.f};
        {
            const ushort_t* ux = xA_lds + lm * XS + 8 * q;
#pragma unroll
            for (int kc = 0; kc < 10; ++kc) {
                bf16x8 b0 = __builtin_bit_cast(bf16x8, *(const u16x8v*)(ux + 32 * kc));
                acc = __builtin_amdgcn_mfma_f32_16x16x32_bf16(aih[kc], b0, acc, 0, 0, 0);
            }
        }
        // land hA
        {
            u64_t* dsth = (u64_t*)(hA_lds + xr * HS);
#pragma unroll
            for (int k = 0; k < 8; ++k) dsth[xln + 16 * k] = htmp[k];
        }
        __syncthreads();   // S2b-A
        if (wv == 0) vB0 = g_load_flag(mfB);   // pre-issue B flag (used this iteration)
        // hh-A
        {
            const ushort_t* uh = hA_lds + lm * HS + 8 * q;
#pragma unroll
            for (int kc = 0; kc < 16; ++kc) {
                bf16x8 b0 = __builtin_bit_cast(bf16x8, *(const u16x8v*)(uh + 32 * kc));
                acc = __builtin_amdgcn_mfma_f32_16x16x32_bf16(ahh[kc], b0, acc, 0, 0, 0);
            }
        }
        // elem-A
        {
            float ig = sigmoidf_(acc.x + bias0);
            float fg = sigmoidf_(acc.y + bias1);
            float gg = tanhf_(acc.z + bias2);
            float og = sigmoidf_(acc.w + bias3);
            cA = fg * cA + ig * gg;
            h_scr[lm * SCR2 + 4 * wv + q] = f2bf(og * tanhf_(cA));
        }
        __syncthreads();   // S3a-A
        if (tid < 64) {
            const int r = tid >> 2;    // batch row 0..15
            const int d = tid & 3;     // u64 0..3 (16 units = 32B)
            u64_t v = *(const u64_t*)((const char*)h_scr + r * (SCR2 * 2) + d * 8);
            ushort_t* hdst = hbuf + (size_t)((t + 1) & 1) * (256 * 512);
            g_store64((u64_t*)(hdst + (size_t)(Bg0A + r) * 512 + U0 + 4 * d), v);
        }
        __syncthreads();   // S3b-A: stores at LLC before publish
        if (tid == 0) g_store_flag(pubA, t + 2);

        // ================= B-half: group B advances step t =================
        if (wv == 0) {
            const int target = t + 1;
            if (!__all(vB0 >= target)) {
                while (true) {
                    int v = g_load_flag(mfB);
                    if (__all(v >= target)) break;
                    __builtin_amdgcn_s_sleep(1);
                }
            }
            asm volatile("" ::: "memory");
        }
        __syncthreads();   // S2a-B

        // issue hB loads
        {
            const u64_t* hsrc = (const u64_t*)(hbuf + (size_t)(t & 1) * (256 * 512)
                                               + (size_t)(Bg0B + xr) * 512);
#pragma unroll
            for (int k = 0; k < 8; ++k) htmp[k] = g_load64(hsrc + xln + 16 * k);
        }
        // stage xA_{t+1} (consumes xpA); refill xpA for t+2
        {
            const bool tz = (tokA_stage != 0);
            unsigned int* dst = (unsigned int*)(xA_lds + xr * XS);
#pragma unroll
            for (int k = 0; k < 10; ++k) {
                int i = xln + 16 * k;
                unsigned int v = 0u;
                if (tz && i < 150)
                    v = (unsigned int)f2bf(xpA[k].x) | ((unsigned int)f2bf(xpA[k].y) << 16);
                dst[i] = v;
            }
            tokA_stage = tokA_nxt;
            const float2* s2 = (const float2*)(emb + (size_t)tokA_stage * 300);
#pragma unroll
            for (int k = 0; k < 10; ++k) { int i = xln + 16 * k; if (i < 150) xpA[k] = s2[i]; }
            tokA_nxt = toksA[(t + 3 < 512) ? (t + 3) : 511];
        }
        // ih-B (hides hB latency)
        acc = (f32x4){0.f, 0.f, 0.f, 0.f};
        {
            const ushort_t* ux = xB_lds + lm * XS + 8 * q;
#pragma unroll
            for (int kc = 0; kc < 10; ++kc) {
                bf16x8 b0 = __builtin_bit_cast(bf16x8, *(const u16x8v*)(ux + 32 * kc));
                acc = __builtin_amdgcn_mfma_f32_16x16x32_bf16(aih[kc], b0, acc, 0, 0, 0);
            }
        }
        // land hB
        {
            u64_t* dsth = (u64_t*)(hB_lds + xr * HS);
#pragma unroll
            for (int k = 0; k < 8; ++k) dsth[xln + 16 * k] = htmp[k];
        }
        __syncthreads();   // S2b-B
        if (wv == 0) vA0 = g_load_flag(mfA);   // pre-issue A flag for next iteration
        // hh-B
        {
            const ushort_t* uh = hB_lds + lm * HS + 8 * q;
#pragma unroll
            for (int kc = 0; kc < 16; ++kc) {
                bf16x8 b0 = __builtin_bit_cast(bf16x8, *(const u16x8v*)(uh + 32 * kc));
                acc = __builtin_amdgcn_mfma_f32_16x16x32_bf16(ahh[kc], b0, acc, 0, 0, 0);
            }
        }
        // elem-B
        {
            float ig = sigmoidf_(acc.x + bias0);
            float fg = sigmoidf_(acc.y + bias1);
            float gg = tanhf_(acc.z + bias2);
            float og = sigmoidf_(acc.w + bias3);
            cB = fg * cB + ig * gg;
            h_scr[lm * SCR2 + 4 * wv + q] = f2bf(og * tanhf_(cB));
        }
        __syncthreads();   // S3a-B
        if (tid < 64) {
            const int r = tid >> 2;
            const int d = tid & 3;
            u64_t v = *(const u64_t*)((const char*)h_scr + r * (SCR2 * 2) + d * 8);
            ushort_t* hdst = hbuf + (size_t)((t + 1) & 1) * (256 * 512);
            g_store64((u64_t*)(hdst + (size_t)(Bg0B + r) * 512 + U0 + 4 * d), v);
        }
        __syncthreads();   // S3b-B
        if (tid == 0) g_store_flag(pubB, t + 2);
    }

    // ---- wait both groups done (513), then FC: block handles batch Bg0A+ib ----
    if (wv == 0) {
        const int* mfFC = &flags[p * 64 + lane];   // lanes 0..63 span A+B flags
        while (true) {
            int v = g_load_flag(mfFC);
            if (__all(v >= 513)) break;
            __builtin_amdgcn_s_sleep(1);
        }
        asm volatile("" ::: "memory");
    }
    __syncthreads();

    {
        const int bb = Bg0A + ib;                       // ib 0..31 covers the pair's 32 batches
        const ushort_t* hrow = hbuf + (size_t)bb * 512; // final h in parity 0
        u64_t h0 = g_load64((const u64_t*)(hrow + lane * 8));
        u64_t h1 = g_load64((const u64_t*)(hrow + lane * 8 + 4));
        float hv[8];
#pragma unroll
        for (int j = 0; j < 4; ++j) hv[j]     = bf2f((ushort_t)(h0 >> (16 * j)));
#pragma unroll
        for (int j = 0; j < 4; ++j) hv[4 + j] = bf2f((ushort_t)(h1 >> (16 * j)));
#pragma unroll
        for (int oo = 0; oo < 2; ++oo) {
            int o = wv + 4 * oo;       // waves 0..3 -> o {0,4},{1,5},{2,6},{3}
            if (o < 7) {
                f32x4 w0 = *(const f32x4*)(Wfc + o * 512 + lane * 8);
                f32x4 w1 = *(const f32x4*)(Wfc + o * 512 + lane * 8 + 4);
                float s = hv[0] * w0.x + hv[1] * w0.y + hv[2] * w0.z + hv[3] * w0.w
                        + hv[4] * w1.x + hv[5] * w1.y + hv[6] * w1.z + hv[7] * w1.w;
#pragma unroll
                for (int sh = 32; sh >= 1; sh >>= 1) s += __shfl_down(s, sh);
                if (lane == 0)
                    out[bb * 7 + o] = s + bfc[o];
            }
        }
    }
}

extern "C" void kernel_launch(void* const* d_in, const int* in_sizes, int n_in,
                              void* d_out, int out_size, void* d_ws, size_t ws_size,
                              hipStream_t stream) {
    const int* tokens = (const int*)d_in[0];
    const float* emb  = (const float*)d_in[1];
    const float* Wih  = (const float*)d_in[2];
    const float* bih  = (const float*)d_in[3];
    const float* Whh  = (const float*)d_in[4];
    const float* bhh  = (const float*)d_in[5];
    const float* Wfc  = (const float*)d_in[6];
    const float* bfc  = (const float*)d_in[7];

    int* flags      = (int*)d_ws;                       // 512 ints: pair p -> [64p..64p+64)
    ushort_t* hbuf  = (ushort_t*)((char*)d_ws + 4096);  // [2][256][512] bf16 = 512 KiB

    lstm_fused_kernel<<<dim3(256), dim3(256), 0, stream>>>(
        tokens, emb, Wih, bih, Whh, bhh, Wfc, bfc,
        (float*)d_out, flags, hbuf);
}